// Round 1
// baseline (135.611 us; speedup 1.0000x reference)
//
#include <hip/hip_runtime.h>

// Problem constants
constexpr int PIX  = 513 * 513;  // 263169 pixels per channel
constexpr int NIN  = 64;
constexpr int NOUT = 64;

// S/D transform:
//   S = over + under, D = over - under
//   A_o = sum_i W[o,i]*S[i],  B_o = sum_i |W[o,i]|*D[i]
//   out_over  = 0.5*(A+B) + bias
//   out_under = 0.5*(A-B) + bias
__global__ __launch_bounds__(256) void combined_bounds_kernel(
    const float* __restrict__ under,
    const float* __restrict__ over,
    const float* __restrict__ W,
    const float* __restrict__ bias,
    float* __restrict__ out_under,
    float* __restrict__ out_over)
{
    __shared__ float Wlds[NOUT * NIN];  // 16 KB

    // Cooperative weight stage: 4096 floats = 1024 float4, 256 threads x 4
    {
        const float4* Wg = (const float4*)W;
        float4*       Ws = (float4*)Wlds;
        const int t = threadIdx.x;
        #pragma unroll
        for (int k = 0; k < 4; ++k)
            Ws[t + 256 * k] = Wg[t + 256 * k];
    }
    __syncthreads();

    const int p = blockIdx.x * 256 + threadIdx.x;
    if (p >= PIX) return;

    // Register-cache this pixel's S/D vectors (128 VGPRs, statically indexed)
    float S[NIN], D[NIN];
    #pragma unroll
    for (int i = 0; i < NIN; ++i) {
        const float ov = over[(size_t)i * PIX + p];
        const float uv = under[(size_t)i * PIX + p];
        S[i] = ov + uv;
        D[i] = ov - uv;
    }

    // 8 chunks of 8 outputs -> 16 accumulators live at a time
    for (int oc = 0; oc < 8; ++oc) {
        float accA[8], accB[8];
        #pragma unroll
        for (int j = 0; j < 8; ++j) { accA[j] = 0.f; accB[j] = 0.f; }

        #pragma unroll
        for (int i = 0; i < NIN; i += 4) {
            #pragma unroll
            for (int j = 0; j < 8; ++j) {
                // Broadcast read (wave-uniform address): W[oc*8+j][i..i+3]
                const float4 w4 = *(const float4*)&Wlds[(oc * 8 + j) * NIN + i];
                accA[j] += w4.x * S[i + 0];
                accB[j] += fabsf(w4.x) * D[i + 0];
                accA[j] += w4.y * S[i + 1];
                accB[j] += fabsf(w4.y) * D[i + 1];
                accA[j] += w4.z * S[i + 2];
                accB[j] += fabsf(w4.z) * D[i + 2];
                accA[j] += w4.w * S[i + 3];
                accB[j] += fabsf(w4.w) * D[i + 3];
            }
        }

        #pragma unroll
        for (int j = 0; j < 8; ++j) {
            const int o = oc * 8 + j;
            const float b  = bias[o];
            const float vo = 0.5f * (accA[j] + accB[j]) + b;
            const float vu = 0.5f * (accA[j] - accB[j]) + b;
            out_over[(size_t)o * PIX + p]  = vo;
            out_under[(size_t)o * PIX + p] = vu;
        }
    }
}

extern "C" void kernel_launch(void* const* d_in, const int* in_sizes, int n_in,
                              void* d_out, int out_size, void* d_ws, size_t ws_size,
                              hipStream_t stream) {
    // setup_inputs order: inputs_under, inputs_over, weights, biases, layer_idx
    const float* under = (const float*)d_in[0];
    const float* over  = (const float*)d_in[1];
    const float* W     = (const float*)d_in[2];
    const float* bias  = (const float*)d_in[3];
    // d_out: (combined_under, combined_over) concatenated flat
    float* out_under = (float*)d_out;
    float* out_over  = out_under + (size_t)NOUT * PIX;

    const int blocks = (PIX + 255) / 256;
    combined_bounds_kernel<<<blocks, 256, 0, stream>>>(under, over, W, bias,
                                                       out_under, out_over);
}